// Round 1
// baseline (968.998 us; speedup 1.0000x reference)
//
#include <hip/hip_runtime.h>
#include <cstdint>
#include <cstddef>

#define NFEAT 500
#define NHID  128
#define NCLASS 40

typedef __attribute__((ext_vector_type(8))) short bf16x8;
typedef __attribute__((ext_vector_type(4))) float f32x4;

__device__ __forceinline__ unsigned short f2bf(float f) {
    union { float f; unsigned u; } v; v.f = f;
    unsigned u = v.u;
    unsigned r = u + 0x7FFF + ((u >> 16) & 1);   // round-to-nearest-even
    return (unsigned short)(r >> 16);
}
__device__ __forceinline__ float bf2f(unsigned short h) {
    union { unsigned u; float f; } v; v.u = ((unsigned)h) << 16; return v.f;
}

// ---------------- CSR construction ----------------

__global__ void k_hist(const int* __restrict__ row, int E, int* __restrict__ counts) {
    int i = blockIdx.x * 256 + threadIdx.x;
    if (i < E) atomicAdd(&counts[row[i]], 1);
}

__global__ void k_block_sum(const int* __restrict__ counts, int n, int* __restrict__ partials) {
    __shared__ int tmp[256];
    int i = blockIdx.x * 256 + threadIdx.x;
    tmp[threadIdx.x] = (i < n) ? counts[i] : 0;
    __syncthreads();
    for (int o = 128; o > 0; o >>= 1) {
        if (threadIdx.x < o) tmp[threadIdx.x] += tmp[threadIdx.x + o];
        __syncthreads();
    }
    if (threadIdx.x == 0) partials[blockIdx.x] = tmp[0];
}

__global__ void k_scan_partials(int* __restrict__ partials, int nb) {
    __shared__ int tmp[512];
    int t = threadIdx.x;
    int v = (t < nb) ? partials[t] : 0;
    tmp[t] = v;
    __syncthreads();
    for (int o = 1; o < 512; o <<= 1) {
        int add = (t >= o) ? tmp[t - o] : 0;
        __syncthreads();
        tmp[t] += add;
        __syncthreads();
    }
    if (t < nb) partials[t] = tmp[t] - v;   // exclusive
}

// also zeroes counts for reuse as cursor
__global__ void k_scan_counts(int* __restrict__ counts, const int* __restrict__ partials,
                              int* __restrict__ row_ptr, int n) {
    __shared__ int tmp[256];
    int t = threadIdx.x;
    int i = blockIdx.x * 256 + t;
    int v = (i < n) ? counts[i] : 0;
    tmp[t] = v;
    __syncthreads();
    for (int o = 1; o < 256; o <<= 1) {
        int add = (t >= o) ? tmp[t - o] : 0;
        __syncthreads();
        tmp[t] += add;
        __syncthreads();
    }
    int incl = tmp[t];
    int base = partials[blockIdx.x];
    if (i < n) {
        row_ptr[i] = base + incl - v;
        counts[i] = 0;
    }
    if (i == n - 1) row_ptr[n] = base + incl;
}

__global__ void k_scatter(const int* __restrict__ row, const int* __restrict__ col,
                          const float* __restrict__ w, int E,
                          const int* __restrict__ row_ptr, int* __restrict__ cursor,
                          uint2* __restrict__ csr_cw) {
    int i = blockIdx.x * 256 + threadIdx.x;
    if (i < E) {
        int r = row[i];
        int p = row_ptr[r] + atomicAdd(&cursor[r], 1);
        csr_cw[p] = make_uint2((unsigned)col[i], __float_as_uint(w[i]));
    }
}

// ---------------- weight prep: W[K][N] fp32 -> Wt[Nt][Kpad] bf16 (transposed, zero-padded) ----------------

__global__ void k_prep_w(const float* __restrict__ W, unsigned short* __restrict__ Wt,
                         int K, int Norig, int Nt, int Kpad) {
    int idx = blockIdx.x * 256 + threadIdx.x;
    if (idx >= Nt * Kpad) return;
    int n = idx / Kpad, k = idx % Kpad;
    unsigned short v = 0;
    if (k < K && n < Norig) v = f2bf(W[(size_t)k * Norig + n]);
    Wt[idx] = v;
}

// ---------------- MFMA GEMM: C[M][CPITCH] = A[M][K] @ Wt^T, bf16 out, fp32 acc ----------------
// BM=128, BK=32, 256 threads (4 waves). Pipeline:
//  - A: 2-deep register prefetch (two static staging sets) -> swizzled LDS double buffer
//  - B: double-buffered register fragments, loaded one iter ahead (L2-hot Wt)
//  - barrier = "s_waitcnt lgkmcnt(0); s_barrier" (NO vmcnt drain -> global prefetch
//    stays in flight across the barrier; compiler inserts counted vmcnt at reg use)
//  - LDS: [128][32] ushorts, 16B-chunk XOR swizzle (c ^= (row>>1)&3) -> 2-way (free)
//    read/write bank pattern instead of the old P=40 8-way group conflict.
// Main loop unrolled x2 so all buffer/set indices are compile-time (no scratch).

#define LDSBAR() asm volatile("s_waitcnt lgkmcnt(0)\n\ts_barrier" ::: "memory")

template<bool AFP32, int BN, int CN, int CPITCH>
__global__ __launch_bounds__(256, 3) void k_gemm_mfma(const void* __restrict__ Ain,
                                                      const unsigned short* __restrict__ Wt,
                                                      unsigned short* __restrict__ C,
                                                      int M, int K, int Kpad) {
    constexpr int NW = (BN == 128) ? 2 : 1;
    constexpr int MW = 4 / NW;
    constexpr int TM = 128 / (MW * 16);
    constexpr int TN = BN / (NW * 16);
    __shared__ __align__(16) unsigned short As[2][128 * 32];   // 16.0 KB total

    const int t = threadIdx.x;
    const int lane = t & 63;
    const int w = t >> 6;
    const int wm = w / NW, wn = w % NW;
    const int mbase = blockIdx.x * 128;
    const int l15 = lane & 15, quad = lane >> 4;

    const float* Af = (const float*)Ain;
    const unsigned short* Ab = (const unsigned short*)Ain;

    f32x4 acc[TM][TN];
#pragma unroll
    for (int mi = 0; mi < TM; mi++)
#pragma unroll
        for (int ni = 0; ni < TN; ni++)
            acc[mi][ni] = (f32x4){0.f, 0.f, 0.f, 0.f};

    // per-thread staging geometry: chunk c = t&3 (16B of k), rows m0 = t>>2 and m0+64
    const int sc = t & 3;
    const int sm = t >> 2;
    const int scs = sc ^ ((sm >> 1) & 3);            // swizzled chunk (same for both rows)

    auto loadA_f = [&](float4* r, int k0) {
        int gk = k0 + sc * 8;
        const float* p0 = Af + (size_t)(mbase + sm) * K + gk;
        const float* p1 = p0 + (size_t)64 * K;
        bool g0 = (mbase + sm) < M;
        bool g1 = (mbase + 64 + sm) < M;
        bool k0ok = gk + 4 <= K, k1ok = gk + 8 <= K;
        float4 z = make_float4(0.f, 0.f, 0.f, 0.f);
        r[0] = (g0 && k0ok) ? *(const float4*)p0 : z;
        r[1] = (g0 && k1ok) ? *(const float4*)(p0 + 4) : z;
        r[2] = (g1 && k0ok) ? *(const float4*)p1 : z;
        r[3] = (g1 && k1ok) ? *(const float4*)(p1 + 4) : z;
    };
    auto loadA_b = [&](uint4* r, int k0) {
        const unsigned short* p0 = Ab + (size_t)(mbase + sm) * Kpad + k0 + sc * 8;
        r[0] = *(const uint4*)p0;
        r[1] = *(const uint4*)(p0 + (size_t)64 * Kpad);
    };
    auto pack8 = [&](float4 a, float4 b) -> uint4 {
        uint4 u;
        u.x = (unsigned)f2bf(a.x) | ((unsigned)f2bf(a.y) << 16);
        u.y = (unsigned)f2bf(a.z) | ((unsigned)f2bf(a.w) << 16);
        u.z = (unsigned)f2bf(b.x) | ((unsigned)f2bf(b.y) << 16);
        u.w = (unsigned)f2bf(b.z) | ((unsigned)f2bf(b.w) << 16);
        return u;
    };
    auto storeLDS = [&](unsigned short* buf, const float4* rf, const uint4* rb) {
        unsigned short* d0 = buf + sm * 32 + scs * 8;
        if (AFP32) {
            *(uint4*)d0 = pack8(rf[0], rf[1]);
            *(uint4*)(d0 + 64 * 32) = pack8(rf[2], rf[3]);
        } else {
            *(uint4*)d0 = rb[0];
            *(uint4*)(d0 + 64 * 32) = rb[1];
        }
    };
    auto loadB = [&](bf16x8* bf, int k0) {
        const unsigned short* bp = Wt + (size_t)(wn * (TN * 16) + l15) * Kpad + k0 + quad * 8;
#pragma unroll
        for (int ni = 0; ni < TN; ni++)
            bf[ni] = *(const bf16x8*)(bp + (size_t)(ni * 16) * Kpad);
    };
    auto compute = [&](const unsigned short* sbuf, const bf16x8* bf) {
        bf16x8 afr[TM];
        const int rcs = quad ^ ((l15 >> 1) & 3);     // read-side swizzle (row bits from l15)
#pragma unroll
        for (int mi = 0; mi < TM; mi++) {
            int r = wm * (TM * 16) + mi * 16 + l15;
            afr[mi] = *(const bf16x8*)(sbuf + r * 32 + rcs * 8);
        }
#pragma unroll
        for (int mi = 0; mi < TM; mi++)
#pragma unroll
            for (int ni = 0; ni < TN; ni++)
                acc[mi][ni] = __builtin_amdgcn_mfma_f32_16x16x32_bf16(afr[mi], bf[ni], acc[mi][ni], 0, 0, 0);
    };

    const int nIter = Kpad >> 5;                     // 16 (layer 1) or 4 (layers 2-4): always even
    float4 raA_f[4], raB_f[4];
    uint4  raA_b[2], raB_b[2];
    bf16x8 bA[TN], bB[TN];

    // prologue: fill set A (it=0), B frags (it=0), prefetch set B (it=1)
    if (AFP32) loadA_f(raA_f, 0); else loadA_b(raA_b, 0);
    loadB(bA, 0);
    if (AFP32) loadA_f(raB_f, 32); else loadA_b(raB_b, 32);
    storeLDS(As[0], raA_f, raA_b);                   // waits only set-A loads (counted vmcnt)
    LDSBAR();

    for (int it = 0; it < nIter; it += 2) {
        // ---- body A: compute it from As[0] with bA ----
        if (it + 2 < nIter) { if (AFP32) loadA_f(raA_f, (it + 2) * 32); else loadA_b(raA_b, (it + 2) * 32); }
        loadB(bB, (it + 1) * 32);
        compute(As[0], bA);
        storeLDS(As[1], raB_f, raB_b);               // data for it+1, loaded 2 bodies ago
        LDSBAR();
        // ---- body B: compute it+1 from As[1] with bB ----
        if (it + 3 < nIter) { if (AFP32) loadA_f(raB_f, (it + 3) * 32); else loadA_b(raB_b, (it + 3) * 32); }
        if (it + 2 < nIter) loadB(bA, (it + 2) * 32);
        compute(As[1], bB);
        if (it + 2 < nIter) {
            storeLDS(As[0], raA_f, raA_b);
            LDSBAR();
        }
    }

    // epilogue: C/D layout col=lane&15, row=quad*4+reg ; rows padded, no M guard
#pragma unroll
    for (int mi = 0; mi < TM; mi++) {
#pragma unroll
        for (int r = 0; r < 4; r++) {
            int gm = mbase + wm * (TM * 16) + mi * 16 + quad * 4 + r;
#pragma unroll
            for (int ni = 0; ni < TN; ni++) {
                int gn = wn * (TN * 16) + ni * 16 + l15;
                if (gn < CN) C[(size_t)gm * CPITCH + gn] = f2bf(acc[mi][ni][r]);
            }
        }
    }
}

// ---------------- SpMM (width 128, bf16) + bias + optional ReLU ----------------

__global__ __launch_bounds__(256) void k_spmm128(const unsigned short* __restrict__ S,
                                                 const int* __restrict__ rp,
                                                 const uint2* __restrict__ cw,
                                                 const float* __restrict__ bias,
                                                 unsigned short* __restrict__ out,
                                                 int n, int do_relu) {
    int wid  = threadIdx.x >> 6;
    int lane = threadIdx.x & 63;
    int node = blockIdx.x * 4 + wid;
    if (node >= n) return;
    int s = rp[node], e = rp[node + 1];
    float a0x = 0.f, a0y = 0.f, a1x = 0.f, a1y = 0.f;
    float a2x = 0.f, a2y = 0.f, a3x = 0.f, a3y = 0.f;
    int i = s;
    for (; i + 4 <= e; i += 4) {
        uint2 e0 = cw[i], e1 = cw[i + 1], e2 = cw[i + 2], e3 = cw[i + 3];
        unsigned v0 = ((const unsigned*)(S + (size_t)e0.x * NHID))[lane];
        unsigned v1 = ((const unsigned*)(S + (size_t)e1.x * NHID))[lane];
        unsigned v2 = ((const unsigned*)(S + (size_t)e2.x * NHID))[lane];
        unsigned v3 = ((const unsigned*)(S + (size_t)e3.x * NHID))[lane];
        float w0 = __uint_as_float(e0.y), w1 = __uint_as_float(e1.y);
        float w2 = __uint_as_float(e2.y), w3 = __uint_as_float(e3.y);
        a0x = fmaf(w0, bf2f((unsigned short)v0), a0x); a0y = fmaf(w0, bf2f((unsigned short)(v0 >> 16)), a0y);
        a1x = fmaf(w1, bf2f((unsigned short)v1), a1x); a1y = fmaf(w1, bf2f((unsigned short)(v1 >> 16)), a1y);
        a2x = fmaf(w2, bf2f((unsigned short)v2), a2x); a2y = fmaf(w2, bf2f((unsigned short)(v2 >> 16)), a2y);
        a3x = fmaf(w3, bf2f((unsigned short)v3), a3x); a3y = fmaf(w3, bf2f((unsigned short)(v3 >> 16)), a3y);
    }
    for (; i < e; i++) {
        uint2 e0 = cw[i];
        unsigned v0 = ((const unsigned*)(S + (size_t)e0.x * NHID))[lane];
        float w0 = __uint_as_float(e0.y);
        a0x = fmaf(w0, bf2f((unsigned short)v0), a0x); a0y = fmaf(w0, bf2f((unsigned short)(v0 >> 16)), a0y);
    }
    float ax = (a0x + a1x) + (a2x + a3x) + bias[lane * 2];
    float ay = (a0y + a1y) + (a2y + a3y) + bias[lane * 2 + 1];
    if (do_relu) {
        ax = fmaxf(ax, 0.f);
        ay = fmaxf(ay, 0.f);
    }
    unsigned o = (unsigned)f2bf(ax) | ((unsigned)f2bf(ay) << 16);
    __builtin_nontemporal_store(o, (unsigned*)(out + (size_t)node * NHID) + lane);
}

// ---------------- SpMM (width 40, bf16 pitch 40) + bias + log_softmax -> fp32 out ----------------

__global__ __launch_bounds__(256) void k_spmm40_lsm(const unsigned short* __restrict__ S,
                                                    const int* __restrict__ rp,
                                                    const uint2* __restrict__ cw,
                                                    const float* __restrict__ bias,
                                                    float* __restrict__ out,
                                                    int n) {
    int wid  = threadIdx.x >> 6;
    int lane = threadIdx.x & 63;
    int node = blockIdx.x * 4 + wid;
    if (node >= n) return;
    int s = rp[node], e = rp[node + 1];
    float a0 = 0.f, a1 = 0.f, a2 = 0.f, a3 = 0.f;
    int i = s;
    bool act = lane < NCLASS;
    for (; i + 4 <= e; i += 4) {
        uint2 e0 = cw[i], e1 = cw[i + 1], e2 = cw[i + 2], e3 = cw[i + 3];
        if (act) {
            float v0 = bf2f(S[(size_t)e0.x * NCLASS + lane]);
            float v1 = bf2f(S[(size_t)e1.x * NCLASS + lane]);
            float v2 = bf2f(S[(size_t)e2.x * NCLASS + lane]);
            float v3 = bf2f(S[(size_t)e3.x * NCLASS + lane]);
            a0 = fmaf(__uint_as_float(e0.y), v0, a0);
            a1 = fmaf(__uint_as_float(e1.y), v1, a1);
            a2 = fmaf(__uint_as_float(e2.y), v2, a2);
            a3 = fmaf(__uint_as_float(e3.y), v3, a3);
        }
    }
    for (; i < e; i++) {
        uint2 e0 = cw[i];
        if (act) a0 = fmaf(__uint_as_float(e0.y), bf2f(S[(size_t)e0.x * NCLASS + lane]), a0);
    }
    float acc = (a0 + a1) + (a2 + a3);
    float logit = act ? acc + bias[lane] : -INFINITY;
    float m = logit;
#pragma unroll
    for (int o = 32; o >= 1; o >>= 1) m = fmaxf(m, __shfl_xor(m, o, 64));
    float ex = act ? expf(logit - m) : 0.f;
    float ssum = ex;
#pragma unroll
    for (int o = 32; o >= 1; o >>= 1) ssum += __shfl_xor(ssum, o, 64);
    if (act) {
        float r = logit - m - logf(ssum);
        __builtin_nontemporal_store(r, out + (size_t)node * NCLASS + lane);
    }
}

// ---------------- launch ----------------

extern "C" void kernel_launch(void* const* d_in, const int* in_sizes, int n_in,
                              void* d_out, int out_size, void* d_ws, size_t ws_size,
                              hipStream_t stream) {
    const float* x  = (const float*)d_in[0];
    const int* row  = (const int*)d_in[1];
    const int* col  = (const int*)d_in[2];
    const float* ew = (const float*)d_in[3];
    const float* W1 = (const float*)d_in[4];
    const float* b1 = (const float*)d_in[5];
    const float* W2 = (const float*)d_in[6];
    const float* b2 = (const float*)d_in[7];
    const float* W3 = (const float*)d_in[8];
    const float* b3 = (const float*)d_in[9];
    const float* W4 = (const float*)d_in[10];
    const float* b4 = (const float*)d_in[11];
    float* out = (float*)d_out;

    const int Nn = in_sizes[0] / NFEAT;
    const int E  = in_sizes[1];
    const int NB = (Nn + 255) / 256;
    const int Mpad = (Nn + 127) & ~127;

    char* ws = (char*)d_ws;
    size_t off = 0;
    auto alloc = [&](size_t bytes) {
        size_t o = off;
        off = (off + bytes + 255) & ~(size_t)255;
        return o;
    };
    int*   row_ptr  = (int*)(ws + alloc((size_t)(Nn + 1) * 4));
    int*   counts   = (int*)(ws + alloc((size_t)Nn * 4));       // also reused as cursor
    int*   partials = (int*)(ws + alloc((size_t)NB * 4));
    uint2* csr_cw   = (uint2*)(ws + alloc((size_t)E * 8));
    unsigned short* Sb  = (unsigned short*)(ws + alloc((size_t)Mpad * NHID * 2));
    unsigned short* Hb  = (unsigned short*)(ws + alloc((size_t)Mpad * NHID * 2));
    unsigned short* S4b = (unsigned short*)(ws + alloc((size_t)Mpad * NCLASS * 2));
    unsigned short* Wt1 = (unsigned short*)(ws + alloc((size_t)128 * 512 * 2));
    unsigned short* Wt2 = (unsigned short*)(ws + alloc((size_t)128 * 128 * 2));
    unsigned short* Wt3 = (unsigned short*)(ws + alloc((size_t)128 * 128 * 2));
    unsigned short* Wt4 = (unsigned short*)(ws + alloc((size_t)48 * 128 * 2));

    // ---- weight prep ----
    k_prep_w<<<(128 * 512 + 255) / 256, 256, 0, stream>>>(W1, Wt1, NFEAT, NHID, 128, 512);
    k_prep_w<<<(128 * 128 + 255) / 256, 256, 0, stream>>>(W2, Wt2, NHID, NHID, 128, 128);
    k_prep_w<<<(128 * 128 + 255) / 256, 256, 0, stream>>>(W3, Wt3, NHID, NHID, 128, 128);
    k_prep_w<<<(48 * 128 + 255) / 256, 256, 0, stream>>>(W4, Wt4, NHID, NCLASS, 48, 128);

    // ---- CSR build ----
    (void)hipMemsetAsync(counts, 0, (size_t)Nn * 4, stream);
    k_hist<<<(E + 255) / 256, 256, 0, stream>>>(row, E, counts);
    k_block_sum<<<NB, 256, 0, stream>>>(counts, Nn, partials);
    k_scan_partials<<<1, 512, 0, stream>>>(partials, NB);
    k_scan_counts<<<NB, 256, 0, stream>>>(counts, partials, row_ptr, Nn);
    k_scatter<<<(E + 255) / 256, 256, 0, stream>>>(row, col, ew, E, row_ptr, counts, csr_cw);

    const int gblocks = Mpad / 128;
    const int spmm_blocks = (Nn + 3) / 4;

    // layer 1: x @ W1 -> Sb ; spmm+b1+relu -> Hb
    k_gemm_mfma<true, 128, 128, 128><<<gblocks, 256, 0, stream>>>(x, Wt1, Sb, Nn, NFEAT, 512);
    k_spmm128<<<spmm_blocks, 256, 0, stream>>>(Sb, row_ptr, csr_cw, b1, Hb, Nn, 1);
    // layer 2
    k_gemm_mfma<false, 128, 128, 128><<<gblocks, 256, 0, stream>>>(Hb, Wt2, Sb, Nn, NHID, NHID);
    k_spmm128<<<spmm_blocks, 256, 0, stream>>>(Sb, row_ptr, csr_cw, b2, Hb, Nn, 1);
    // layer 3
    k_gemm_mfma<false, 128, 128, 128><<<gblocks, 256, 0, stream>>>(Hb, Wt3, Sb, Nn, NHID, NHID);
    k_spmm128<<<spmm_blocks, 256, 0, stream>>>(Sb, row_ptr, csr_cw, b3, Hb, Nn, 1);
    // layer 4: Hb @ W4 -> S4b[N,40] ; spmm+b4+log_softmax -> out (fp32)
    k_gemm_mfma<false, 48, 40, 40><<<gblocks, 256, 0, stream>>>(Hb, Wt4, S4b, Nn, NHID, NHID);
    k_spmm40_lsm<<<spmm_blocks, 256, 0, stream>>>(S4b, row_ptr, csr_cw, b4, out, Nn);
}

// Round 2
// 894.521 us; speedup vs baseline: 1.0833x; 1.0833x over previous
//
#include <hip/hip_runtime.h>
#include <cstdint>
#include <cstddef>

#define NFEAT 500
#define NHID  128
#define NCLASS 40

typedef __attribute__((ext_vector_type(8))) short bf16x8;
typedef __attribute__((ext_vector_type(4))) float f32x4;

__device__ __forceinline__ unsigned short f2bf(float f) {
    union { float f; unsigned u; } v; v.f = f;
    unsigned u = v.u;
    unsigned r = u + 0x7FFF + ((u >> 16) & 1);   // round-to-nearest-even
    return (unsigned short)(r >> 16);
}
__device__ __forceinline__ float bf2f(unsigned short h) {
    union { unsigned u; float f; } v; v.u = ((unsigned)h) << 16; return v.f;
}

// ---------------- CSR construction ----------------

__global__ void k_hist(const int* __restrict__ row, int E, int* __restrict__ counts) {
    int i = blockIdx.x * 256 + threadIdx.x;
    if (i < E) atomicAdd(&counts[row[i]], 1);
}

__global__ void k_block_sum(const int* __restrict__ counts, int n, int* __restrict__ partials) {
    __shared__ int tmp[256];
    int i = blockIdx.x * 256 + threadIdx.x;
    tmp[threadIdx.x] = (i < n) ? counts[i] : 0;
    __syncthreads();
    for (int o = 128; o > 0; o >>= 1) {
        if (threadIdx.x < o) tmp[threadIdx.x] += tmp[threadIdx.x + o];
        __syncthreads();
    }
    if (threadIdx.x == 0) partials[blockIdx.x] = tmp[0];
}

__global__ void k_scan_partials(int* __restrict__ partials, int nb) {
    __shared__ int tmp[512];
    int t = threadIdx.x;
    int v = (t < nb) ? partials[t] : 0;
    tmp[t] = v;
    __syncthreads();
    for (int o = 1; o < 512; o <<= 1) {
        int add = (t >= o) ? tmp[t - o] : 0;
        __syncthreads();
        tmp[t] += add;
        __syncthreads();
    }
    if (t < nb) partials[t] = tmp[t] - v;   // exclusive
}

// also zeroes counts for reuse as cursor
__global__ void k_scan_counts(int* __restrict__ counts, const int* __restrict__ partials,
                              int* __restrict__ row_ptr, int n) {
    __shared__ int tmp[256];
    int t = threadIdx.x;
    int i = blockIdx.x * 256 + t;
    int v = (i < n) ? counts[i] : 0;
    tmp[t] = v;
    __syncthreads();
    for (int o = 1; o < 256; o <<= 1) {
        int add = (t >= o) ? tmp[t - o] : 0;
        __syncthreads();
        tmp[t] += add;
        __syncthreads();
    }
    int incl = tmp[t];
    int base = partials[blockIdx.x];
    if (i < n) {
        row_ptr[i] = base + incl - v;
        counts[i] = 0;
    }
    if (i == n - 1) row_ptr[n] = base + incl;
}

__global__ void k_scatter(const int* __restrict__ row, const int* __restrict__ col,
                          const float* __restrict__ w, int E,
                          const int* __restrict__ row_ptr, int* __restrict__ cursor,
                          uint2* __restrict__ csr_cw) {
    int i = blockIdx.x * 256 + threadIdx.x;
    if (i < E) {
        int r = row[i];
        int p = row_ptr[r] + atomicAdd(&cursor[r], 1);
        csr_cw[p] = make_uint2((unsigned)col[i], __float_as_uint(w[i]));
    }
}

// ---------------- weight prep: W[K][N] fp32 -> Wt[Nt][Kpad] bf16 (transposed, zero-padded) ----------------

__global__ void k_prep_w(const float* __restrict__ W, unsigned short* __restrict__ Wt,
                         int K, int Norig, int Nt, int Kpad) {
    int idx = blockIdx.x * 256 + threadIdx.x;
    if (idx >= Nt * Kpad) return;
    int n = idx / Kpad, k = idx % Kpad;
    unsigned short v = 0;
    if (k < K && n < Norig) v = f2bf(W[(size_t)k * Norig + n]);
    Wt[idx] = v;
}

// ---------------- MFMA GEMM: C[M][CPITCH] = A[M][K] @ Wt^T, bf16 out, fp32 acc ----------------
// BM=128, BK=32, 256 threads (4 waves). Pipeline (round-1 schedule, scratch-proofed):
//  - A: 2-deep register prefetch in NAMED scalar regs (no arrays across call
//    boundaries -> SROA trivially promotes; round-1's pointer-param lambdas leaked
//    116 MB of scratch writes) -> swizzled LDS double buffer
//  - B: double-buffered register fragments, loaded one iter ahead (L2-hot Wt)
//  - barrier = "s_waitcnt lgkmcnt(0); s_barrier": no vmcnt drain, global prefetch
//    stays in flight across the barrier (compiler inserts counted vmcnt at use)
//  - LDS: [128][32] ushorts, 16B-chunk XOR swizzle (c ^= (row>>1)&3): verified
//    SQ_LDS_BANK_CONFLICT == 0 on HW (round 1)
//  - NO __launch_bounds__ min-wave cap (round-1's (256,3) pressured the allocator)
// Main loop unrolled x2 so all buffer/set selections are compile-time.

#define LDSBAR() asm volatile("s_waitcnt lgkmcnt(0)\n\ts_barrier" ::: "memory")

__device__ __forceinline__ uint4 pack8(float4 a, float4 b) {
    uint4 u;
    u.x = (unsigned)f2bf(a.x) | ((unsigned)f2bf(a.y) << 16);
    u.y = (unsigned)f2bf(a.z) | ((unsigned)f2bf(a.w) << 16);
    u.z = (unsigned)f2bf(b.x) | ((unsigned)f2bf(b.y) << 16);
    u.w = (unsigned)f2bf(b.z) | ((unsigned)f2bf(b.w) << 16);
    return u;
}

// load one 32-wide K-slice of A into named regs (fp32: 4x float4, bf16: 2x uint4)
#define LOADA(F0, F1, F2, F3, U0, U1, K0)                                         \
    do {                                                                          \
        if constexpr (AFP32) {                                                    \
            int gk_ = (K0) + sc * 8;                                              \
            const float* p_ = apf + (K0);                                         \
            float4 z_ = make_float4(0.f, 0.f, 0.f, 0.f);                          \
            F0 = (g0 && gk_ + 4 <= K) ? *(const float4*)p_ : z_;                  \
            F1 = (g0 && gk_ + 8 <= K) ? *(const float4*)(p_ + 4) : z_;            \
            F2 = (g1 && gk_ + 4 <= K) ? *(const float4*)(p_ + (size_t)64 * K) : z_;       \
            F3 = (g1 && gk_ + 8 <= K) ? *(const float4*)(p_ + (size_t)64 * K + 4) : z_;   \
        } else {                                                                  \
            U0 = *(const uint4*)(apb + (K0));                                     \
            U1 = *(const uint4*)(apb + (K0) + (size_t)64 * Kpad);                 \
        }                                                                         \
    } while (0)

#define STOREA(BUF, F0, F1, F2, F3, U0, U1)                                       \
    do {                                                                          \
        if constexpr (AFP32) {                                                    \
            *(uint4*)&(BUF)[soff] = pack8(F0, F1);                                \
            *(uint4*)&(BUF)[soff + 64 * 32] = pack8(F2, F3);                      \
        } else {                                                                  \
            *(uint4*)&(BUF)[soff] = U0;                                           \
            *(uint4*)&(BUF)[soff + 64 * 32] = U1;                                 \
        }                                                                         \
    } while (0)

#define LOADB(BF, K0)                                                             \
    do {                                                                          \
        _Pragma("unroll")                                                         \
        for (int ni_ = 0; ni_ < TN; ni_++)                                        \
            BF[ni_] = *(const bf16x8*)(bp + (size_t)(ni_ * 16) * Kpad + (K0));    \
    } while (0)

#define COMPUTE(BUF, BF)                                                          \
    do {                                                                          \
        bf16x8 afr_[TM];                                                          \
        _Pragma("unroll")                                                         \
        for (int mi_ = 0; mi_ < TM; mi_++)                                        \
            afr_[mi_] = *(const bf16x8*)&(BUF)[(wm * (TM * 16) + mi_ * 16 + l15) * 32 + rcs * 8]; \
        _Pragma("unroll")                                                         \
        for (int mi_ = 0; mi_ < TM; mi_++)                                        \
            _Pragma("unroll")                                                     \
            for (int ni_ = 0; ni_ < TN; ni_++)                                    \
                acc[mi_][ni_] = __builtin_amdgcn_mfma_f32_16x16x32_bf16(afr_[mi_], BF[ni_], acc[mi_][ni_], 0, 0, 0); \
    } while (0)

template<bool AFP32, int BN, int CN, int CPITCH>
__global__ __launch_bounds__(256) void k_gemm_mfma(const void* __restrict__ Ain,
                                                   const unsigned short* __restrict__ Wt,
                                                   unsigned short* __restrict__ C,
                                                   int M, int K, int Kpad) {
    constexpr int NW = (BN == 128) ? 2 : 1;
    constexpr int MW = 4 / NW;
    constexpr int TM = 128 / (MW * 16);
    constexpr int TN = BN / (NW * 16);
    __shared__ __align__(16) unsigned short As[2][128 * 32];   // 16.0 KB total

    const int t = threadIdx.x;
    const int lane = t & 63;
    const int w = t >> 6;
    const int wm = w / NW, wn = w % NW;
    const int mbase = blockIdx.x * 128;
    const int l15 = lane & 15, quad = lane >> 4;

    const float* Af = (const float*)Ain;
    const unsigned short* Ab = (const unsigned short*)Ain;

    f32x4 acc[TM][TN];
#pragma unroll
    for (int mi = 0; mi < TM; mi++)
#pragma unroll
        for (int ni = 0; ni < TN; ni++)
            acc[mi][ni] = (f32x4){0.f, 0.f, 0.f, 0.f};

    // staging geometry: chunk sc = t&3 (16B of k), rows sm = t>>2 and sm+64
    const int sc = t & 3;
    const int sm = t >> 2;
    const int scs = sc ^ ((sm >> 1) & 3);            // swizzled chunk (same both rows)
    const int soff = sm * 32 + scs * 8;
    const int rcs = quad ^ ((l15 >> 1) & 3);         // read-side swizzle

    const float* apf = Af + (size_t)(mbase + sm) * K + sc * 8;
    const unsigned short* apb = Ab + (size_t)(mbase + sm) * Kpad + sc * 8;
    const unsigned short* bp = Wt + (size_t)(wn * (TN * 16) + l15) * Kpad + quad * 8;
    const bool g0 = (mbase + sm) < M;
    const bool g1 = (mbase + 64 + sm) < M;

    const int nIter = Kpad >> 5;                     // 16 (layer 1) or 4 (layers 2-4): even

    // named staging registers, two sets
    float4 fA0, fA1, fA2, fA3, fB0, fB1, fB2, fB3;
    uint4  uA0, uA1, uB0, uB1;
    bf16x8 bA[TN], bB[TN];

    // prologue: fill set A (it=0), B frags (it=0), prefetch set B (it=1)
    LOADA(fA0, fA1, fA2, fA3, uA0, uA1, 0);
    LOADB(bA, 0);
    LOADA(fB0, fB1, fB2, fB3, uB0, uB1, 32);
    STOREA(As[0], fA0, fA1, fA2, fA3, uA0, uA1);     // waits only set-A loads
    LDSBAR();

    for (int it = 0; it < nIter; it += 2) {
        // ---- body A: compute it from As[0] with bA ----
        if (it + 2 < nIter) LOADA(fA0, fA1, fA2, fA3, uA0, uA1, (it + 2) * 32);
        LOADB(bB, (it + 1) * 32);
        COMPUTE(As[0], bA);
        STOREA(As[1], fB0, fB1, fB2, fB3, uB0, uB1); // data for it+1, loaded 2 bodies ago
        LDSBAR();
        // ---- body B: compute it+1 from As[1] with bB ----
        if (it + 3 < nIter) LOADA(fB0, fB1, fB2, fB3, uB0, uB1, (it + 3) * 32);
        if (it + 2 < nIter) LOADB(bA, (it + 2) * 32);
        COMPUTE(As[1], bB);
        if (it + 2 < nIter) {
            STOREA(As[0], fA0, fA1, fA2, fA3, uA0, uA1);
            LDSBAR();
        }
    }

    // epilogue: C/D layout col=lane&15, row=quad*4+reg ; rows padded, no M guard
#pragma unroll
    for (int mi = 0; mi < TM; mi++) {
#pragma unroll
        for (int r = 0; r < 4; r++) {
            int gm = mbase + wm * (TM * 16) + mi * 16 + quad * 4 + r;
#pragma unroll
            for (int ni = 0; ni < TN; ni++) {
                int gn = wn * (TN * 16) + ni * 16 + l15;
                if (gn < CN) C[(size_t)gm * CPITCH + gn] = f2bf(acc[mi][ni][r]);
            }
        }
    }
}

// ---------------- SpMM (width 128, bf16) + bias + optional ReLU ----------------

__global__ __launch_bounds__(256) void k_spmm128(const unsigned short* __restrict__ S,
                                                 const int* __restrict__ rp,
                                                 const uint2* __restrict__ cw,
                                                 const float* __restrict__ bias,
                                                 unsigned short* __restrict__ out,
                                                 int n, int do_relu) {
    int wid  = threadIdx.x >> 6;
    int lane = threadIdx.x & 63;
    int node = blockIdx.x * 4 + wid;
    if (node >= n) return;
    int s = rp[node], e = rp[node + 1];
    float a0x = 0.f, a0y = 0.f, a1x = 0.f, a1y = 0.f;
    float a2x = 0.f, a2y = 0.f, a3x = 0.f, a3y = 0.f;
    int i = s;
    for (; i + 4 <= e; i += 4) {
        uint2 e0 = cw[i], e1 = cw[i + 1], e2 = cw[i + 2], e3 = cw[i + 3];
        unsigned v0 = ((const unsigned*)(S + (size_t)e0.x * NHID))[lane];
        unsigned v1 = ((const unsigned*)(S + (size_t)e1.x * NHID))[lane];
        unsigned v2 = ((const unsigned*)(S + (size_t)e2.x * NHID))[lane];
        unsigned v3 = ((const unsigned*)(S + (size_t)e3.x * NHID))[lane];
        float w0 = __uint_as_float(e0.y), w1 = __uint_as_float(e1.y);
        float w2 = __uint_as_float(e2.y), w3 = __uint_as_float(e3.y);
        a0x = fmaf(w0, bf2f((unsigned short)v0), a0x); a0y = fmaf(w0, bf2f((unsigned short)(v0 >> 16)), a0y);
        a1x = fmaf(w1, bf2f((unsigned short)v1), a1x); a1y = fmaf(w1, bf2f((unsigned short)(v1 >> 16)), a1y);
        a2x = fmaf(w2, bf2f((unsigned short)v2), a2x); a2y = fmaf(w2, bf2f((unsigned short)(v2 >> 16)), a2y);
        a3x = fmaf(w3, bf2f((unsigned short)v3), a3x); a3y = fmaf(w3, bf2f((unsigned short)(v3 >> 16)), a3y);
    }
    for (; i < e; i++) {
        uint2 e0 = cw[i];
        unsigned v0 = ((const unsigned*)(S + (size_t)e0.x * NHID))[lane];
        float w0 = __uint_as_float(e0.y);
        a0x = fmaf(w0, bf2f((unsigned short)v0), a0x); a0y = fmaf(w0, bf2f((unsigned short)(v0 >> 16)), a0y);
    }
    float ax = (a0x + a1x) + (a2x + a3x) + bias[lane * 2];
    float ay = (a0y + a1y) + (a2y + a3y) + bias[lane * 2 + 1];
    if (do_relu) {
        ax = fmaxf(ax, 0.f);
        ay = fmaxf(ay, 0.f);
    }
    unsigned o = (unsigned)f2bf(ax) | ((unsigned)f2bf(ay) << 16);
    __builtin_nontemporal_store(o, (unsigned*)(out + (size_t)node * NHID) + lane);
}

// ---------------- SpMM (width 40, bf16 pitch 40) + bias + log_softmax -> fp32 out ----------------

__global__ __launch_bounds__(256) void k_spmm40_lsm(const unsigned short* __restrict__ S,
                                                    const int* __restrict__ rp,
                                                    const uint2* __restrict__ cw,
                                                    const float* __restrict__ bias,
                                                    float* __restrict__ out,
                                                    int n) {
    int wid  = threadIdx.x >> 6;
    int lane = threadIdx.x & 63;
    int node = blockIdx.x * 4 + wid;
    if (node >= n) return;
    int s = rp[node], e = rp[node + 1];
    float a0 = 0.f, a1 = 0.f, a2 = 0.f, a3 = 0.f;
    int i = s;
    bool act = lane < NCLASS;
    for (; i + 4 <= e; i += 4) {
        uint2 e0 = cw[i], e1 = cw[i + 1], e2 = cw[i + 2], e3 = cw[i + 3];
        if (act) {
            float v0 = bf2f(S[(size_t)e0.x * NCLASS + lane]);
            float v1 = bf2f(S[(size_t)e1.x * NCLASS + lane]);
            float v2 = bf2f(S[(size_t)e2.x * NCLASS + lane]);
            float v3 = bf2f(S[(size_t)e3.x * NCLASS + lane]);
            a0 = fmaf(__uint_as_float(e0.y), v0, a0);
            a1 = fmaf(__uint_as_float(e1.y), v1, a1);
            a2 = fmaf(__uint_as_float(e2.y), v2, a2);
            a3 = fmaf(__uint_as_float(e3.y), v3, a3);
        }
    }
    for (; i < e; i++) {
        uint2 e0 = cw[i];
        if (act) a0 = fmaf(__uint_as_float(e0.y), bf2f(S[(size_t)e0.x * NCLASS + lane]), a0);
    }
    float acc = (a0 + a1) + (a2 + a3);
    float logit = act ? acc + bias[lane] : -INFINITY;
    float m = logit;
#pragma unroll
    for (int o = 32; o >= 1; o >>= 1) m = fmaxf(m, __shfl_xor(m, o, 64));
    float ex = act ? expf(logit - m) : 0.f;
    float ssum = ex;
#pragma unroll
    for (int o = 32; o >= 1; o >>= 1) ssum += __shfl_xor(ssum, o, 64);
    if (act) {
        float r = logit - m - logf(ssum);
        __builtin_nontemporal_store(r, out + (size_t)node * NCLASS + lane);
    }
}

// ---------------- launch ----------------

extern "C" void kernel_launch(void* const* d_in, const int* in_sizes, int n_in,
                              void* d_out, int out_size, void* d_ws, size_t ws_size,
                              hipStream_t stream) {
    const float* x  = (const float*)d_in[0];
    const int* row  = (const int*)d_in[1];
    const int* col  = (const int*)d_in[2];
    const float* ew = (const float*)d_in[3];
    const float* W1 = (const float*)d_in[4];
    const float* b1 = (const float*)d_in[5];
    const float* W2 = (const float*)d_in[6];
    const float* b2 = (const float*)d_in[7];
    const float* W3 = (const float*)d_in[8];
    const float* b3 = (const float*)d_in[9];
    const float* W4 = (const float*)d_in[10];
    const float* b4 = (const float*)d_in[11];
    float* out = (float*)d_out;

    const int Nn = in_sizes[0] / NFEAT;
    const int E  = in_sizes[1];
    const int NB = (Nn + 255) / 256;
    const int Mpad = (Nn + 127) & ~127;

    char* ws = (char*)d_ws;
    size_t off = 0;
    auto alloc = [&](size_t bytes) {
        size_t o = off;
        off = (off + bytes + 255) & ~(size_t)255;
        return o;
    };
    int*   row_ptr  = (int*)(ws + alloc((size_t)(Nn + 1) * 4));
    int*   counts   = (int*)(ws + alloc((size_t)Nn * 4));       // also reused as cursor
    int*   partials = (int*)(ws + alloc((size_t)NB * 4));
    uint2* csr_cw   = (uint2*)(ws + alloc((size_t)E * 8));
    unsigned short* Sb  = (unsigned short*)(ws + alloc((size_t)Mpad * NHID * 2));
    unsigned short* Hb  = (unsigned short*)(ws + alloc((size_t)Mpad * NHID * 2));
    unsigned short* S4b = (unsigned short*)(ws + alloc((size_t)Mpad * NCLASS * 2));
    unsigned short* Wt1 = (unsigned short*)(ws + alloc((size_t)128 * 512 * 2));
    unsigned short* Wt2 = (unsigned short*)(ws + alloc((size_t)128 * 128 * 2));
    unsigned short* Wt3 = (unsigned short*)(ws + alloc((size_t)128 * 128 * 2));
    unsigned short* Wt4 = (unsigned short*)(ws + alloc((size_t)48 * 128 * 2));

    // ---- weight prep ----
    k_prep_w<<<(128 * 512 + 255) / 256, 256, 0, stream>>>(W1, Wt1, NFEAT, NHID, 128, 512);
    k_prep_w<<<(128 * 128 + 255) / 256, 256, 0, stream>>>(W2, Wt2, NHID, NHID, 128, 128);
    k_prep_w<<<(128 * 128 + 255) / 256, 256, 0, stream>>>(W3, Wt3, NHID, NHID, 128, 128);
    k_prep_w<<<(48 * 128 + 255) / 256, 256, 0, stream>>>(W4, Wt4, NHID, NCLASS, 48, 128);

    // ---- CSR build ----
    (void)hipMemsetAsync(counts, 0, (size_t)Nn * 4, stream);
    k_hist<<<(E + 255) / 256, 256, 0, stream>>>(row, E, counts);
    k_block_sum<<<NB, 256, 0, stream>>>(counts, Nn, partials);
    k_scan_partials<<<1, 512, 0, stream>>>(partials, NB);
    k_scan_counts<<<NB, 256, 0, stream>>>(counts, partials, row_ptr, Nn);
    k_scatter<<<(E + 255) / 256, 256, 0, stream>>>(row, col, ew, E, row_ptr, counts, csr_cw);

    const int gblocks = Mpad / 128;
    const int spmm_blocks = (Nn + 3) / 4;

    // layer 1: x @ W1 -> Sb ; spmm+b1+relu -> Hb
    k_gemm_mfma<true, 128, 128, 128><<<gblocks, 256, 0, stream>>>(x, Wt1, Sb, Nn, NFEAT, 512);
    k_spmm128<<<spmm_blocks, 256, 0, stream>>>(Sb, row_ptr, csr_cw, b1, Hb, Nn, 1);
    // layer 2
    k_gemm_mfma<false, 128, 128, 128><<<gblocks, 256, 0, stream>>>(Hb, Wt2, Sb, Nn, NHID, NHID);
    k_spmm128<<<spmm_blocks, 256, 0, stream>>>(Sb, row_ptr, csr_cw, b2, Hb, Nn, 1);
    // layer 3
    k_gemm_mfma<false, 128, 128, 128><<<gblocks, 256, 0, stream>>>(Hb, Wt3, Sb, Nn, NHID, NHID);
    k_spmm128<<<spmm_blocks, 256, 0, stream>>>(Sb, row_ptr, csr_cw, b3, Hb, Nn, 1);
    // layer 4: Hb @ W4 -> S4b[N,40] ; spmm+b4+log_softmax -> out (fp32)
    k_gemm_mfma<false, 48, 40, 40><<<gblocks, 256, 0, stream>>>(Hb, Wt4, S4b, Nn, NHID, NHID);
    k_spmm40_lsm<<<spmm_blocks, 256, 0, stream>>>(S4b, row_ptr, csr_cw, b4, out, Nn);
}

// Round 3
// 884.402 us; speedup vs baseline: 1.0957x; 1.0114x over previous
//
#include <hip/hip_runtime.h>
#include <cstdint>
#include <cstddef>

#define NFEAT 500
#define NHID  128
#define NCLASS 40

typedef __attribute__((ext_vector_type(8))) short bf16x8;
typedef __attribute__((ext_vector_type(4))) float f32x4;

__device__ __forceinline__ unsigned short f2bf(float f) {
    union { float f; unsigned u; } v; v.f = f;
    unsigned u = v.u;
    unsigned r = u + 0x7FFF + ((u >> 16) & 1);   // round-to-nearest-even
    return (unsigned short)(r >> 16);
}
__device__ __forceinline__ float bf2f(unsigned short h) {
    union { unsigned u; float f; } v; v.u = ((unsigned)h) << 16; return v.f;
}

__device__ __forceinline__ bf16x8 cvt8(float4 a, float4 b) {
    union { bf16x8 v; unsigned u[4]; } r;
    r.u[0] = (unsigned)f2bf(a.x) | ((unsigned)f2bf(a.y) << 16);
    r.u[1] = (unsigned)f2bf(a.z) | ((unsigned)f2bf(a.w) << 16);
    r.u[2] = (unsigned)f2bf(b.x) | ((unsigned)f2bf(b.y) << 16);
    r.u[3] = (unsigned)f2bf(b.z) | ((unsigned)f2bf(b.w) << 16);
    return r.v;
}

// ---------------- CSR construction ----------------

__global__ void k_hist(const int* __restrict__ row, int E, int* __restrict__ counts) {
    int i = blockIdx.x * 256 + threadIdx.x;
    if (i < E) atomicAdd(&counts[row[i]], 1);
}

__global__ void k_block_sum(const int* __restrict__ counts, int n, int* __restrict__ partials) {
    __shared__ int tmp[256];
    int i = blockIdx.x * 256 + threadIdx.x;
    tmp[threadIdx.x] = (i < n) ? counts[i] : 0;
    __syncthreads();
    for (int o = 128; o > 0; o >>= 1) {
        if (threadIdx.x < o) tmp[threadIdx.x] += tmp[threadIdx.x + o];
        __syncthreads();
    }
    if (threadIdx.x == 0) partials[blockIdx.x] = tmp[0];
}

__global__ void k_scan_partials(int* __restrict__ partials, int nb) {
    __shared__ int tmp[512];
    int t = threadIdx.x;
    int v = (t < nb) ? partials[t] : 0;
    tmp[t] = v;
    __syncthreads();
    for (int o = 1; o < 512; o <<= 1) {
        int add = (t >= o) ? tmp[t - o] : 0;
        __syncthreads();
        tmp[t] += add;
        __syncthreads();
    }
    if (t < nb) partials[t] = tmp[t] - v;   // exclusive
}

// also zeroes counts for reuse as cursor
__global__ void k_scan_counts(int* __restrict__ counts, const int* __restrict__ partials,
                              int* __restrict__ row_ptr, int n) {
    __shared__ int tmp[256];
    int t = threadIdx.x;
    int i = blockIdx.x * 256 + t;
    int v = (i < n) ? counts[i] : 0;
    tmp[t] = v;
    __syncthreads();
    for (int o = 1; o < 256; o <<= 1) {
        int add = (t >= o) ? tmp[t - o] : 0;
        __syncthreads();
        tmp[t] += add;
        __syncthreads();
    }
    int incl = tmp[t];
    int base = partials[blockIdx.x];
    if (i < n) {
        row_ptr[i] = base + incl - v;
        counts[i] = 0;
    }
    if (i == n - 1) row_ptr[n] = base + incl;
}

__global__ void k_scatter(const int* __restrict__ row, const int* __restrict__ col,
                          const float* __restrict__ w, int E,
                          const int* __restrict__ row_ptr, int* __restrict__ cursor,
                          uint2* __restrict__ csr_cw) {
    int i = blockIdx.x * 256 + threadIdx.x;
    if (i < E) {
        int r = row[i];
        int p = row_ptr[r] + atomicAdd(&cursor[r], 1);
        csr_cw[p] = make_uint2((unsigned)col[i], __float_as_uint(w[i]));
    }
}

// ---------------- weight prep: W[K][N] fp32 -> Wt[Nt][Kpad] bf16 (transposed, zero-padded) ----------------

__global__ void k_prep_w(const float* __restrict__ W, unsigned short* __restrict__ Wt,
                         int K, int Norig, int Nt, int Kpad) {
    int idx = blockIdx.x * 256 + threadIdx.x;
    if (idx >= Nt * Kpad) return;
    int n = idx / Kpad, k = idx % Kpad;
    unsigned short v = 0;
    if (k < K && n < Norig) v = f2bf(W[(size_t)k * Norig + n]);
    Wt[idx] = v;
}

// ---------------- Direct MFMA GEMM: no LDS, no barriers ----------------
// Structural insight: BN == full N, so each A-row is consumed by exactly ONE wave
// -> zero A-reuse -> LDS staging moves bytes global->reg->LDS->reg for no traffic
// reduction, and its barriers lockstep 4 waves onto the slowest load (rounds 0-2:
// 117/223/161 us, all latency-bound, every pipe <11% busy).
// Here each wave owns a 32 x BN output tile, fragments loaded straight from global:
//  - A frag: 16 lanes x 16B at row*K + quad*8 -> 16 full 64B lines per load, each
//    A element read exactly once globally. fp32 path converts to bf16 in VALU.
//  - B frags: Wt is [n][k] = exact MFMA B layout; Wt2/3/4 (32KB) L1-resident,
//    Wt1 (128KB) L2-resident.
// Low regs (~64 acc + ~32 B + addr) -> 3 waves/SIMD; grid 3128 waves = 12/CU of
// pure TLP. No syncs of any kind.

template<bool AFP32, int BN, int CN, int CPITCH>
__global__ __launch_bounds__(256) void k_gemm_direct(const void* __restrict__ Ain,
                                                     const unsigned short* __restrict__ Wt,
                                                     unsigned short* __restrict__ C,
                                                     int M, int K, int Kpad) {
    constexpr int TM = 2;                 // 32 rows per wave
    constexpr int TN = BN / 16;           // 8 (BN=128) or 3 (BN=48)
    const int t = threadIdx.x;
    const int lane = t & 63;
    const int l15 = lane & 15, quad = lane >> 4;
    const int wave = blockIdx.x * 4 + (t >> 6);
    const int m0 = wave * 32;

    const float* Af = (const float*)Ain;
    const unsigned short* Ab = (const unsigned short*)Ain;

    f32x4 acc[TM][TN];
#pragma unroll
    for (int mi = 0; mi < TM; mi++)
#pragma unroll
        for (int ni = 0; ni < TN; ni++)
            acc[mi][ni] = (f32x4){0.f, 0.f, 0.f, 0.f};

    // row indices; fp32 path clamps OOB rows (A sized exactly M*K) and zeros result
    const int r0 = m0 + l15, r1 = m0 + 16 + l15;
    bool g0 = true, g1 = true;
    int rc0 = r0, rc1 = r1;
    if constexpr (AFP32) {
        g0 = r0 < M; g1 = r1 < M;
        rc0 = g0 ? r0 : M - 1;
        rc1 = g1 ? r1 : M - 1;
    }

    const unsigned short* bp = Wt + (size_t)l15 * Kpad + quad * 8;

    const int nFull = K >> 5;
#pragma unroll 2
    for (int it = 0; it < nFull; it++) {
        const int k0 = it << 5;
        bf16x8 bfr[TN];
#pragma unroll
        for (int ni = 0; ni < TN; ni++)
            bfr[ni] = *(const bf16x8*)(bp + (size_t)(ni * 16) * Kpad + k0);
        bf16x8 afr[TM];
        if constexpr (AFP32) {
            const float* p0 = Af + (size_t)rc0 * K + k0 + quad * 8;
            const float* p1 = Af + (size_t)rc1 * K + k0 + quad * 8;
            float4 x0 = *(const float4*)p0, x1 = *(const float4*)(p0 + 4);
            float4 y0 = *(const float4*)p1, y1 = *(const float4*)(p1 + 4);
            float4 z = make_float4(0.f, 0.f, 0.f, 0.f);
            if (!g0) { x0 = z; x1 = z; }
            if (!g1) { y0 = z; y1 = z; }
            afr[0] = cvt8(x0, x1);
            afr[1] = cvt8(y0, y1);
        } else {
            afr[0] = *(const bf16x8*)(Ab + (size_t)r0 * Kpad + k0 + quad * 8);
            afr[1] = *(const bf16x8*)(Ab + (size_t)r1 * Kpad + k0 + quad * 8);
        }
#pragma unroll
        for (int mi = 0; mi < TM; mi++)
#pragma unroll
            for (int ni = 0; ni < TN; ni++)
                acc[mi][ni] = __builtin_amdgcn_mfma_f32_16x16x32_bf16(afr[mi], bfr[ni], acc[mi][ni], 0, 0, 0);
    }

    if constexpr (AFP32) {
        if (K & 31) {                      // K tail (layer 1: k0=480, K=500)
            const int k0 = nFull << 5;
            bf16x8 bfr[TN];
#pragma unroll
            for (int ni = 0; ni < TN; ni++)
                bfr[ni] = *(const bf16x8*)(bp + (size_t)(ni * 16) * Kpad + k0);  // Wt zero-padded
            float va[8], vb[8];
#pragma unroll
            for (int j = 0; j < 8; j++) {
                int gk = k0 + quad * 8 + j;
                bool kk = gk < K;
                va[j] = (g0 && kk) ? Af[(size_t)rc0 * K + gk] : 0.f;
                vb[j] = (g1 && kk) ? Af[(size_t)rc1 * K + gk] : 0.f;
            }
            bf16x8 afr[TM];
            afr[0] = cvt8(make_float4(va[0], va[1], va[2], va[3]), make_float4(va[4], va[5], va[6], va[7]));
            afr[1] = cvt8(make_float4(vb[0], vb[1], vb[2], vb[3]), make_float4(vb[4], vb[5], vb[6], vb[7]));
#pragma unroll
            for (int mi = 0; mi < TM; mi++)
#pragma unroll
                for (int ni = 0; ni < TN; ni++)
                    acc[mi][ni] = __builtin_amdgcn_mfma_f32_16x16x32_bf16(afr[mi], bfr[ni], acc[mi][ni], 0, 0, 0);
        }
    }

    // epilogue: C/D layout col=lane&15, row=quad*4+reg ; C rows padded, no M guard
#pragma unroll
    for (int mi = 0; mi < TM; mi++) {
#pragma unroll
        for (int r = 0; r < 4; r++) {
            int gm = m0 + mi * 16 + quad * 4 + r;
#pragma unroll
            for (int ni = 0; ni < TN; ni++) {
                int gn = ni * 16 + l15;
                if (gn < CN) C[(size_t)gm * CPITCH + gn] = f2bf(acc[mi][ni][r]);
            }
        }
    }
}

// ---------------- SpMM (width 128, bf16) + bias + optional ReLU ----------------

__global__ __launch_bounds__(256) void k_spmm128(const unsigned short* __restrict__ S,
                                                 const int* __restrict__ rp,
                                                 const uint2* __restrict__ cw,
                                                 const float* __restrict__ bias,
                                                 unsigned short* __restrict__ out,
                                                 int n, int do_relu) {
    int wid  = threadIdx.x >> 6;
    int lane = threadIdx.x & 63;
    int node = blockIdx.x * 4 + wid;
    if (node >= n) return;
    int s = rp[node], e = rp[node + 1];
    float a0x = 0.f, a0y = 0.f, a1x = 0.f, a1y = 0.f;
    float a2x = 0.f, a2y = 0.f, a3x = 0.f, a3y = 0.f;
    int i = s;
    for (; i + 4 <= e; i += 4) {
        uint2 e0 = cw[i], e1 = cw[i + 1], e2 = cw[i + 2], e3 = cw[i + 3];
        unsigned v0 = ((const unsigned*)(S + (size_t)e0.x * NHID))[lane];
        unsigned v1 = ((const unsigned*)(S + (size_t)e1.x * NHID))[lane];
        unsigned v2 = ((const unsigned*)(S + (size_t)e2.x * NHID))[lane];
        unsigned v3 = ((const unsigned*)(S + (size_t)e3.x * NHID))[lane];
        float w0 = __uint_as_float(e0.y), w1 = __uint_as_float(e1.y);
        float w2 = __uint_as_float(e2.y), w3 = __uint_as_float(e3.y);
        a0x = fmaf(w0, bf2f((unsigned short)v0), a0x); a0y = fmaf(w0, bf2f((unsigned short)(v0 >> 16)), a0y);
        a1x = fmaf(w1, bf2f((unsigned short)v1), a1x); a1y = fmaf(w1, bf2f((unsigned short)(v1 >> 16)), a1y);
        a2x = fmaf(w2, bf2f((unsigned short)v2), a2x); a2y = fmaf(w2, bf2f((unsigned short)(v2 >> 16)), a2y);
        a3x = fmaf(w3, bf2f((unsigned short)v3), a3x); a3y = fmaf(w3, bf2f((unsigned short)(v3 >> 16)), a3y);
    }
    for (; i < e; i++) {
        uint2 e0 = cw[i];
        unsigned v0 = ((const unsigned*)(S + (size_t)e0.x * NHID))[lane];
        float w0 = __uint_as_float(e0.y);
        a0x = fmaf(w0, bf2f((unsigned short)v0), a0x); a0y = fmaf(w0, bf2f((unsigned short)(v0 >> 16)), a0y);
    }
    float ax = (a0x + a1x) + (a2x + a3x) + bias[lane * 2];
    float ay = (a0y + a1y) + (a2y + a3y) + bias[lane * 2 + 1];
    if (do_relu) {
        ax = fmaxf(ax, 0.f);
        ay = fmaxf(ay, 0.f);
    }
    unsigned o = (unsigned)f2bf(ax) | ((unsigned)f2bf(ay) << 16);
    __builtin_nontemporal_store(o, (unsigned*)(out + (size_t)node * NHID) + lane);
}

// ---------------- SpMM (width 40, bf16 pitch 40) + bias + log_softmax -> fp32 out ----------------

__global__ __launch_bounds__(256) void k_spmm40_lsm(const unsigned short* __restrict__ S,
                                                    const int* __restrict__ rp,
                                                    const uint2* __restrict__ cw,
                                                    const float* __restrict__ bias,
                                                    float* __restrict__ out,
                                                    int n) {
    int wid  = threadIdx.x >> 6;
    int lane = threadIdx.x & 63;
    int node = blockIdx.x * 4 + wid;
    if (node >= n) return;
    int s = rp[node], e = rp[node + 1];
    float a0 = 0.f, a1 = 0.f, a2 = 0.f, a3 = 0.f;
    int i = s;
    bool act = lane < NCLASS;
    for (; i + 4 <= e; i += 4) {
        uint2 e0 = cw[i], e1 = cw[i + 1], e2 = cw[i + 2], e3 = cw[i + 3];
        if (act) {
            float v0 = bf2f(S[(size_t)e0.x * NCLASS + lane]);
            float v1 = bf2f(S[(size_t)e1.x * NCLASS + lane]);
            float v2 = bf2f(S[(size_t)e2.x * NCLASS + lane]);
            float v3 = bf2f(S[(size_t)e3.x * NCLASS + lane]);
            a0 = fmaf(__uint_as_float(e0.y), v0, a0);
            a1 = fmaf(__uint_as_float(e1.y), v1, a1);
            a2 = fmaf(__uint_as_float(e2.y), v2, a2);
            a3 = fmaf(__uint_as_float(e3.y), v3, a3);
        }
    }
    for (; i < e; i++) {
        uint2 e0 = cw[i];
        if (act) a0 = fmaf(__uint_as_float(e0.y), bf2f(S[(size_t)e0.x * NCLASS + lane]), a0);
    }
    float acc = (a0 + a1) + (a2 + a3);
    float logit = act ? acc + bias[lane] : -INFINITY;
    float m = logit;
#pragma unroll
    for (int o = 32; o >= 1; o >>= 1) m = fmaxf(m, __shfl_xor(m, o, 64));
    float ex = act ? expf(logit - m) : 0.f;
    float ssum = ex;
#pragma unroll
    for (int o = 32; o >= 1; o >>= 1) ssum += __shfl_xor(ssum, o, 64);
    if (act) {
        float r = logit - m - logf(ssum);
        __builtin_nontemporal_store(r, out + (size_t)node * NCLASS + lane);
    }
}

// ---------------- launch ----------------

extern "C" void kernel_launch(void* const* d_in, const int* in_sizes, int n_in,
                              void* d_out, int out_size, void* d_ws, size_t ws_size,
                              hipStream_t stream) {
    const float* x  = (const float*)d_in[0];
    const int* row  = (const int*)d_in[1];
    const int* col  = (const int*)d_in[2];
    const float* ew = (const float*)d_in[3];
    const float* W1 = (const float*)d_in[4];
    const float* b1 = (const float*)d_in[5];
    const float* W2 = (const float*)d_in[6];
    const float* b2 = (const float*)d_in[7];
    const float* W3 = (const float*)d_in[8];
    const float* b3 = (const float*)d_in[9];
    const float* W4 = (const float*)d_in[10];
    const float* b4 = (const float*)d_in[11];
    float* out = (float*)d_out;

    const int Nn = in_sizes[0] / NFEAT;
    const int E  = in_sizes[1];
    const int NB = (Nn + 255) / 256;
    const int Mpad = (Nn + 127) & ~127;

    char* ws = (char*)d_ws;
    size_t off = 0;
    auto alloc = [&](size_t bytes) {
        size_t o = off;
        off = (off + bytes + 255) & ~(size_t)255;
        return o;
    };
    int*   row_ptr  = (int*)(ws + alloc((size_t)(Nn + 1) * 4));
    int*   counts   = (int*)(ws + alloc((size_t)Nn * 4));       // also reused as cursor
    int*   partials = (int*)(ws + alloc((size_t)NB * 4));
    uint2* csr_cw   = (uint2*)(ws + alloc((size_t)E * 8));
    unsigned short* Sb  = (unsigned short*)(ws + alloc((size_t)Mpad * NHID * 2));
    unsigned short* Hb  = (unsigned short*)(ws + alloc((size_t)Mpad * NHID * 2));
    unsigned short* S4b = (unsigned short*)(ws + alloc((size_t)Mpad * NCLASS * 2));
    unsigned short* Wt1 = (unsigned short*)(ws + alloc((size_t)128 * 512 * 2));
    unsigned short* Wt2 = (unsigned short*)(ws + alloc((size_t)128 * 128 * 2));
    unsigned short* Wt3 = (unsigned short*)(ws + alloc((size_t)128 * 128 * 2));
    unsigned short* Wt4 = (unsigned short*)(ws + alloc((size_t)48 * 128 * 2));

    // ---- weight prep ----
    k_prep_w<<<(128 * 512 + 255) / 256, 256, 0, stream>>>(W1, Wt1, NFEAT, NHID, 128, 512);
    k_prep_w<<<(128 * 128 + 255) / 256, 256, 0, stream>>>(W2, Wt2, NHID, NHID, 128, 128);
    k_prep_w<<<(128 * 128 + 255) / 256, 256, 0, stream>>>(W3, Wt3, NHID, NHID, 128, 128);
    k_prep_w<<<(48 * 128 + 255) / 256, 256, 0, stream>>>(W4, Wt4, NHID, NCLASS, 48, 128);

    // ---- CSR build ----
    (void)hipMemsetAsync(counts, 0, (size_t)Nn * 4, stream);
    k_hist<<<(E + 255) / 256, 256, 0, stream>>>(row, E, counts);
    k_block_sum<<<NB, 256, 0, stream>>>(counts, Nn, partials);
    k_scan_partials<<<1, 512, 0, stream>>>(partials, NB);
    k_scan_counts<<<NB, 256, 0, stream>>>(counts, partials, row_ptr, Nn);
    k_scatter<<<(E + 255) / 256, 256, 0, stream>>>(row, col, ew, E, row_ptr, counts, csr_cw);

    const int gblocks = Mpad / 128;             // 4 waves/block x 32 rows/wave
    const int spmm_blocks = (Nn + 3) / 4;

    // layer 1: x @ W1 -> Sb ; spmm+b1+relu -> Hb
    k_gemm_direct<true, 128, 128, 128><<<gblocks, 256, 0, stream>>>(x, Wt1, Sb, Nn, NFEAT, 512);
    k_spmm128<<<spmm_blocks, 256, 0, stream>>>(Sb, row_ptr, csr_cw, b1, Hb, Nn, 1);
    // layer 2
    k_gemm_direct<false, 128, 128, 128><<<gblocks, 256, 0, stream>>>(Hb, Wt2, Sb, Nn, NHID, NHID);
    k_spmm128<<<spmm_blocks, 256, 0, stream>>>(Sb, row_ptr, csr_cw, b2, Hb, Nn, 1);
    // layer 3
    k_gemm_direct<false, 128, 128, 128><<<gblocks, 256, 0, stream>>>(Hb, Wt3, Sb, Nn, NHID, NHID);
    k_spmm128<<<spmm_blocks, 256, 0, stream>>>(Sb, row_ptr, csr_cw, b3, Hb, Nn, 1);
    // layer 4: Hb @ W4 -> S4b[N,40] ; spmm+b4+log_softmax -> out (fp32)
    k_gemm_direct<false, 48, 40, 40><<<gblocks, 256, 0, stream>>>(Hb, Wt4, S4b, Nn, NHID, NHID);
    k_spmm40_lsm<<<spmm_blocks, 256, 0, stream>>>(S4b, row_ptr, csr_cw, b4, out, Nn);
}